// Round 2
// baseline (12772.535 us; speedup 1.0000x reference)
//
#include <hip/hip_runtime.h>

#define BATCH 1024
#define TT    200
#define EE    100
#define HH    200
#define GG    600   // 3*HH
#define NI    50000
#define KP4   25    // 25 groups of 8 k-values (200 k total)

typedef _Float16 h8v __attribute__((ext_vector_type(8)));
typedef _Float16 h2v __attribute__((ext_vector_type(2)));

#if __has_builtin(__builtin_amdgcn_fdot2)
static __device__ __forceinline__ float fdot2(h2v a, h2v b, float c) {
    return __builtin_amdgcn_fdot2(a, b, c, false);
}
#else
static __device__ __forceinline__ float fdot2(h2v a, h2v b, float c) {
    return c + (float)a.x * (float)b.x + (float)a.y * (float)b.y;
}
#endif

#define SH2(v, d) ((h2v)__builtin_shufflevector((v), (v), 2*(d), 2*(d)+1))

// ---------------- K1: EWi'[v][c] = (v==0 ? 0 : embed[v]@Wi[:,c]) + bi[c] ----------------
__global__ __launch_bounds__(640) void ewi_kernel(const float* __restrict__ embed,
                                                  const float* __restrict__ Wi,
                                                  const float* __restrict__ bi,
                                                  float* __restrict__ EWi) {
    __shared__ __align__(16) float emb_s[32][EE];
    const int i0  = blockIdx.x * 32;
    const int tid = threadIdx.x;
    for (int idx = tid; idx < 32 * EE; idx += 640) {
        int r = idx / EE, e = idx % EE;
        int gr = i0 + r;
        emb_s[r][e] = (gr < NI) ? embed[(size_t)gr * EE + e] : 0.f;
    }
    __syncthreads();
    const int j = tid;
    if (j < GG) {
        float acc[32];
        #pragma unroll
        for (int r = 0; r < 32; ++r) acc[r] = 0.f;
        for (int e = 0; e < EE; ++e) {
            float w = Wi[(size_t)e * GG + j];
            #pragma unroll
            for (int r = 0; r < 32; ++r) acc[r] += emb_s[r][e] * w;
        }
        const float bij = bi[j];
        int rmax = (NI - i0) < 32 ? (NI - i0) : 32;
        for (int r = 0; r < rmax; ++r) {
            float v = (i0 + r == 0) ? 0.f : acc[r];
            EWi[(size_t)(i0 + r) * GG + j] = v + bij;
        }
    }
}

// ---------------- K1b: repack Wh -> fp16, Whp[kp4][c] = 8 halves Wh[8kp4+0..7][c] ----------------
__global__ __launch_bounds__(600) void repack_wh(const float* __restrict__ Wh,
                                                 h8v* __restrict__ Whp) {
    const int c   = threadIdx.x;       // 0..599
    const int kp4 = blockIdx.x;        // 0..24
    h8v w;
    #pragma unroll
    for (int j = 0; j < 8; ++j)
        w[j] = (_Float16)Wh[(size_t)(8 * kp4 + j) * GG + c];
    Whp[(size_t)kp4 * GG + c] = w;
}

// ---------------- K2: persistent GRU scan ----------------
// 768 threads = 12 waves: thread (g = tid>>8, i = tid&255), active if i<200.
// Thread (g,i) owns Wh column c = g*200+i for 4 batch rows; h kept in LDS as fp16;
// inner product via v_dot2_f32_f16 with fp32 accumulate.
__global__ __launch_bounds__(768) void scan_kernel(const int* __restrict__ q,
                                                   const float* __restrict__ EWi,
                                                   const h8v* __restrict__ Whp,
                                                   const float* __restrict__ bhn,
                                                   float* __restrict__ h_out) {
    __shared__ __align__(16) _Float16 h16[4][208];   // fp16 hidden state, padded stride
    __shared__ float r_l[4][HH];
    __shared__ float z_l[4][HH];
    __shared__ float ni_l[4][HH];
    __shared__ float nh_l[4][HH];

    const int tid = threadIdx.x;
    const int g   = tid >> 8;          // 0,1,2
    const int i   = tid & 255;
    const bool act = (i < HH);
    const int c   = g * HH + (act ? i : 0);   // clamped for safe loads
    const int b0  = blockIdx.x * 4;

    for (int idx = tid; idx < 4 * 208; idx += 768) ((_Float16*)h16)[idx] = (_Float16)0.f;
    const float bhn_i = (g == 2 && act) ? bhn[i] : 0.f;
    const h8v* __restrict__ wcol = Whp + c;
    __syncthreads();

    for (int t = 0; t < TT; ++t) {
        // ---- gather gi (branch-free: bias folded, row 0 zeroed) ----
        float gi[4];
        #pragma unroll
        for (int b = 0; b < 4; ++b) {
            int qv = q[(size_t)(b0 + b) * TT + t];
            gi[b] = EWi[(size_t)qv * GG + c];
        }
        // ---- gh = h @ Wh[:,c] via fp16 dot2, fp32 accumulate ----
        float acc0[4], acc1[4];
        #pragma unroll
        for (int b = 0; b < 4; ++b) {
            acc0[b] = (g == 2) ? 0.f : gi[b];   // n-gate keeps gi separate
            acc1[b] = 0.f;
        }
        for (int kp = 0; kp < KP4; ++kp) {
            const h8v w = wcol[(size_t)kp * GG];
            #pragma unroll
            for (int b = 0; b < 4; ++b) {
                const h8v hv = *(const h8v*)(&h16[b][kp * 8]);
                acc0[b] = fdot2(SH2(hv, 0), SH2(w, 0), acc0[b]);
                acc1[b] = fdot2(SH2(hv, 1), SH2(w, 1), acc1[b]);
                acc0[b] = fdot2(SH2(hv, 2), SH2(w, 2), acc0[b]);
                acc1[b] = fdot2(SH2(hv, 3), SH2(w, 3), acc1[b]);
            }
        }
        // ---- per-gate activation + exchange via LDS ----
        if (act) {
            #pragma unroll
            for (int b = 0; b < 4; ++b) {
                float a = acc0[b] + acc1[b];
                if (g == 0)      r_l[b][i] = 1.f / (1.f + __expf(-a));
                else if (g == 1) z_l[b][i] = 1.f / (1.f + __expf(-a));
                else { ni_l[b][i] = gi[b]; nh_l[b][i] = a + bhn_i; }
            }
        }
        __syncthreads();
        // ---- combine (threads 0..199) ----
        if (tid < HH) {
            #pragma unroll
            for (int b = 0; b < 4; ++b) {
                float r    = r_l[b][tid];
                float z    = z_l[b][tid];
                float n    = tanhf(ni_l[b][tid] + r * nh_l[b][tid]);
                float hold = (float)h16[b][tid];
                h16[b][tid] = (_Float16)((1.f - z) * n + z * hold);
            }
        }
        __syncthreads();
    }

    if (tid < HH) {
        #pragma unroll
        for (int b = 0; b < 4; ++b)
            h_out[(size_t)(b0 + b) * HH + tid] = (float)h16[b][tid];
    }
}

// ---------------- K3: out = h_last @ Wo + bo ----------------
__global__ __launch_bounds__(256) void out_kernel(const float* __restrict__ h,
                                                  const float* __restrict__ Wo,
                                                  const float* __restrict__ bo,
                                                  float* __restrict__ out) {
    __shared__ __align__(16) float hs[32][HH];
    const int tid   = threadIdx.x;
    const int col0  = blockIdx.x * 64;
    const int brow0 = blockIdx.y * 32;

    for (int idx = tid; idx < 32 * HH; idx += 256) {
        int r = idx / HH, k = idx % HH;
        hs[r][k] = h[(size_t)(brow0 + r) * HH + k];
    }
    __syncthreads();

    const int col = col0 + (tid & 63);
    const int cc  = col < NI ? col : (NI - 1);
    const int bg  = tid >> 6;

    float acc[8];
    #pragma unroll
    for (int b = 0; b < 8; ++b) acc[b] = 0.f;

    for (int k4 = 0; k4 < HH / 4; ++k4) {
        float w0 = Wo[(size_t)(k4 * 4 + 0) * NI + cc];
        float w1 = Wo[(size_t)(k4 * 4 + 1) * NI + cc];
        float w2 = Wo[(size_t)(k4 * 4 + 2) * NI + cc];
        float w3 = Wo[(size_t)(k4 * 4 + 3) * NI + cc];
        #pragma unroll
        for (int b = 0; b < 8; ++b) {
            const float4 hv = *(const float4*)(&hs[bg * 8 + b][k4 * 4]);
            acc[b] += hv.x * w0;
            acc[b] += hv.y * w1;
            acc[b] += hv.z * w2;
            acc[b] += hv.w * w3;
        }
    }

    if (col < NI) {
        const float bov = bo[col];
        #pragma unroll
        for (int b = 0; b < 8; ++b)
            out[(size_t)(brow0 + bg * 8 + b) * NI + col] = acc[b] + bov;
    }
}

extern "C" void kernel_launch(void* const* d_in, const int* in_sizes, int n_in,
                              void* d_out, int out_size, void* d_ws, size_t ws_size,
                              hipStream_t stream) {
    const int*   q     = (const int*)d_in[0];
    const float* embed = (const float*)d_in[1];
    const float* Wi    = (const float*)d_in[2];
    const float* bi    = (const float*)d_in[3];
    const float* Wh    = (const float*)d_in[4];
    const float* bhn   = (const float*)d_in[5];
    const float* Wo    = (const float*)d_in[6];
    const float* bo    = (const float*)d_in[7];
    float* out = (float*)d_out;

    // Scratch layout:
    //   EWi  [50000 x 600] f32 = 120,000,000 B at d_out+0 (consumed before K3 writes)
    //   Whp  [25 x 600] h8v    = 240,000 B at d_out+120,000,000
    //   h_last [1024 x 200] f32 = 819,200 B in d_ws (proven to fit)
    float* EWi  = out;
    h8v*   Whp  = (h8v*)((char*)d_out + 120000000);
    float* hbuf = (float*)d_ws;

    ewi_kernel<<<(NI + 31) / 32, 640, 0, stream>>>(embed, Wi, bi, EWi);
    repack_wh<<<KP4, GG, 0, stream>>>(Wh, Whp);
    scan_kernel<<<BATCH / 4, 768, 0, stream>>>(q, EWi, Whp, bhn, hbuf);
    out_kernel<<<dim3((NI + 63) / 64, BATCH / 32), 256, 0, stream>>>(hbuf, Wo, bo, out);
}

// Round 3
// 1974.972 us; speedup vs baseline: 6.4672x; 6.4672x over previous
//
#include <hip/hip_runtime.h>

#define BATCH 1024
#define TT    200
#define EE    100
#define HH    200
#define GG    600   // 3*HH
#define NI    50000
#define KP4   25    // 25 groups of 8 k-values (200 k total)

typedef _Float16 h8v __attribute__((ext_vector_type(8)));
typedef _Float16 h2v __attribute__((ext_vector_type(2)));

#if __has_builtin(__builtin_amdgcn_fdot2)
static __device__ __forceinline__ float fdot2(h2v a, h2v b, float c) {
    return __builtin_amdgcn_fdot2(a, b, c, false);
}
#else
static __device__ __forceinline__ float fdot2(h2v a, h2v b, float c) {
    return c + (float)a.x * (float)b.x + (float)a.y * (float)b.y;
}
#endif

#define SH2(v, d) ((h2v)__builtin_shufflevector((v), (v), 2*(d), 2*(d)+1))

// ---------------- K1: EWi'[v][c] = (v==0 ? 0 : embed[v]@Wi[:,c]) + bi[c] ----------------
__global__ __launch_bounds__(640) void ewi_kernel(const float* __restrict__ embed,
                                                  const float* __restrict__ Wi,
                                                  const float* __restrict__ bi,
                                                  float* __restrict__ EWi) {
    __shared__ __align__(16) float emb_s[32][EE];
    const int i0  = blockIdx.x * 32;
    const int tid = threadIdx.x;
    for (int idx = tid; idx < 32 * EE; idx += 640) {
        int r = idx / EE, e = idx % EE;
        int gr = i0 + r;
        emb_s[r][e] = (gr < NI) ? embed[(size_t)gr * EE + e] : 0.f;
    }
    __syncthreads();
    const int j = tid;
    if (j < GG) {
        float acc[32];
        #pragma unroll
        for (int r = 0; r < 32; ++r) acc[r] = 0.f;
        for (int e = 0; e < EE; ++e) {
            float w = Wi[(size_t)e * GG + j];
            #pragma unroll
            for (int r = 0; r < 32; ++r) acc[r] += emb_s[r][e] * w;
        }
        const float bij = bi[j];
        int rmax = (NI - i0) < 32 ? (NI - i0) : 32;
        for (int r = 0; r < rmax; ++r) {
            float v = (i0 + r == 0) ? 0.f : acc[r];
            EWi[(size_t)(i0 + r) * GG + j] = v + bij;
        }
    }
}

// ---------------- K1b: repack Wh -> fp16, Whp[kp4][c] = 8 halves Wh[8kp4+0..7][c] ----------------
__global__ __launch_bounds__(600) void repack_wh(const float* __restrict__ Wh,
                                                 h8v* __restrict__ Whp) {
    const int c   = threadIdx.x;       // 0..599
    const int kp4 = blockIdx.x;        // 0..24
    h8v w;
    #pragma unroll
    for (int j = 0; j < 8; ++j)
        w[j] = (_Float16)Wh[(size_t)(8 * kp4 + j) * GG + c];
    Whp[(size_t)kp4 * GG + c] = w;
}

// ---------------- K2: persistent GRU scan ----------------
// 768 threads = 12 waves = 3 waves/SIMD (1 block/CU). Thread (g = tid>>8, i = tid&255),
// active if i<200, owns Wh column c = g*200+i for 4 batch rows. h kept in LDS as fp16;
// inner product via v_dot2_f32_f16 with fp32 accumulate.
// __launch_bounds__(768, 3): 3 waves/EU is the true occupancy -> VGPR cap ~170.
// Round-2 lesson: default launch_bounds capped VGPRs at 84 -> inner-loop spill,
// 19 GB scratch traffic, 4% VALUBusy. Bound the kp unroll to keep live range small.
__global__ __launch_bounds__(768, 3) void scan_kernel(const int* __restrict__ q,
                                                      const float* __restrict__ EWi,
                                                      const h8v* __restrict__ Whp,
                                                      const float* __restrict__ bhn,
                                                      float* __restrict__ h_out) {
    __shared__ __align__(16) _Float16 h16[4][208];   // fp16 hidden state, padded stride
    __shared__ float r_l[4][HH];
    __shared__ float z_l[4][HH];
    __shared__ float ni_l[4][HH];
    __shared__ float nh_l[4][HH];

    const int tid = threadIdx.x;
    const int g   = tid >> 8;          // 0,1,2
    const int i   = tid & 255;
    const bool act = (i < HH);
    const int c   = g * HH + (act ? i : 0);   // clamped for safe loads
    const int b0  = blockIdx.x * 4;

    for (int idx = tid; idx < 4 * 208; idx += 768) ((_Float16*)h16)[idx] = (_Float16)0.f;
    const float bhn_i = (g == 2 && act) ? bhn[i] : 0.f;
    const h8v* __restrict__ wcol = Whp + c;
    __syncthreads();

    for (int t = 0; t < TT; ++t) {
        // ---- gather gi (branch-free: bias folded, row 0 zeroed) ----
        float gi[4];
        #pragma unroll
        for (int b = 0; b < 4; ++b) {
            int qv = q[(size_t)(b0 + b) * TT + t];
            gi[b] = EWi[(size_t)qv * GG + c];
        }
        // ---- gh = h @ Wh[:,c] via fp16 dot2, fp32 accumulate ----
        float acc0[4], acc1[4];
        #pragma unroll
        for (int b = 0; b < 4; ++b) {
            acc0[b] = (g == 2) ? 0.f : gi[b];   // n-gate keeps gi separate
            acc1[b] = 0.f;
        }
        #pragma unroll 2
        for (int kp = 0; kp < KP4; ++kp) {
            const h8v w = wcol[(size_t)kp * GG];
            #pragma unroll
            for (int b = 0; b < 4; ++b) {
                const h8v hv = *(const h8v*)(&h16[b][kp * 8]);
                acc0[b] = fdot2(SH2(hv, 0), SH2(w, 0), acc0[b]);
                acc1[b] = fdot2(SH2(hv, 1), SH2(w, 1), acc1[b]);
                acc0[b] = fdot2(SH2(hv, 2), SH2(w, 2), acc0[b]);
                acc1[b] = fdot2(SH2(hv, 3), SH2(w, 3), acc1[b]);
            }
        }
        // ---- per-gate activation + exchange via LDS ----
        if (act) {
            #pragma unroll
            for (int b = 0; b < 4; ++b) {
                float a = acc0[b] + acc1[b];
                if (g == 0)      r_l[b][i] = 1.f / (1.f + __expf(-a));
                else if (g == 1) z_l[b][i] = 1.f / (1.f + __expf(-a));
                else { ni_l[b][i] = gi[b]; nh_l[b][i] = a + bhn_i; }
            }
        }
        __syncthreads();
        // ---- combine (threads 0..199) ----
        if (tid < HH) {
            #pragma unroll
            for (int b = 0; b < 4; ++b) {
                float r    = r_l[b][tid];
                float z    = z_l[b][tid];
                float n    = tanhf(ni_l[b][tid] + r * nh_l[b][tid]);
                float hold = (float)h16[b][tid];
                h16[b][tid] = (_Float16)((1.f - z) * n + z * hold);
            }
        }
        __syncthreads();
    }

    if (tid < HH) {
        #pragma unroll
        for (int b = 0; b < 4; ++b)
            h_out[(size_t)(b0 + b) * HH + tid] = (float)h16[b][tid];
    }
}

// ---------------- K3: out = h_last @ Wo + bo ----------------
__global__ __launch_bounds__(256) void out_kernel(const float* __restrict__ h,
                                                  const float* __restrict__ Wo,
                                                  const float* __restrict__ bo,
                                                  float* __restrict__ out) {
    __shared__ __align__(16) float hs[32][HH];
    const int tid   = threadIdx.x;
    const int col0  = blockIdx.x * 64;
    const int brow0 = blockIdx.y * 32;

    for (int idx = tid; idx < 32 * HH; idx += 256) {
        int r = idx / HH, k = idx % HH;
        hs[r][k] = h[(size_t)(brow0 + r) * HH + k];
    }
    __syncthreads();

    const int col = col0 + (tid & 63);
    const int cc  = col < NI ? col : (NI - 1);
    const int bg  = tid >> 6;

    float acc[8];
    #pragma unroll
    for (int b = 0; b < 8; ++b) acc[b] = 0.f;

    for (int k4 = 0; k4 < HH / 4; ++k4) {
        float w0 = Wo[(size_t)(k4 * 4 + 0) * NI + cc];
        float w1 = Wo[(size_t)(k4 * 4 + 1) * NI + cc];
        float w2 = Wo[(size_t)(k4 * 4 + 2) * NI + cc];
        float w3 = Wo[(size_t)(k4 * 4 + 3) * NI + cc];
        #pragma unroll
        for (int b = 0; b < 8; ++b) {
            const float4 hv = *(const float4*)(&hs[bg * 8 + b][k4 * 4]);
            acc[b] += hv.x * w0;
            acc[b] += hv.y * w1;
            acc[b] += hv.z * w2;
            acc[b] += hv.w * w3;
        }
    }

    if (col < NI) {
        const float bov = bo[col];
        #pragma unroll
        for (int b = 0; b < 8; ++b)
            out[(size_t)(brow0 + bg * 8 + b) * NI + col] = acc[b] + bov;
    }
}

extern "C" void kernel_launch(void* const* d_in, const int* in_sizes, int n_in,
                              void* d_out, int out_size, void* d_ws, size_t ws_size,
                              hipStream_t stream) {
    const int*   q     = (const int*)d_in[0];
    const float* embed = (const float*)d_in[1];
    const float* Wi    = (const float*)d_in[2];
    const float* bi    = (const float*)d_in[3];
    const float* Wh    = (const float*)d_in[4];
    const float* bhn   = (const float*)d_in[5];
    const float* Wo    = (const float*)d_in[6];
    const float* bo    = (const float*)d_in[7];
    float* out = (float*)d_out;

    // Scratch layout:
    //   EWi  [50000 x 600] f32 = 120,000,000 B at d_out+0 (consumed before K3 writes)
    //   Whp  [25 x 600] h8v    = 240,000 B at d_out+120,000,000
    //   h_last [1024 x 200] f32 = 819,200 B in d_ws
    float* EWi  = out;
    h8v*   Whp  = (h8v*)((char*)d_out + 120000000);
    float* hbuf = (float*)d_ws;

    ewi_kernel<<<(NI + 31) / 32, 640, 0, stream>>>(embed, Wi, bi, EWi);
    repack_wh<<<KP4, GG, 0, stream>>>(Wh, Whp);
    scan_kernel<<<BATCH / 4, 768, 0, stream>>>(q, EWi, Whp, bhn, hbuf);
    out_kernel<<<dim3((NI + 63) / 64, BATCH / 32), 256, 0, stream>>>(hbuf, Wo, bo, out);
}

// Round 4
// 856.855 us; speedup vs baseline: 14.9063x; 2.3049x over previous
//
#include <hip/hip_runtime.h>

#define BATCH 1024
#define TT    200
#define EE    100
#define HH    200
#define GG    600   // 3*HH
#define NI    50000
#define NKT   7     // k-tiles: 224 = 7*32 (K=200 padded)
#define KPAD  224
#define HSTR  232   // LDS row stride in f16 (464 B = 29*16B, kills 8-way bank conflict)
#define NTILE3 3125 // 50000/16 output n-tiles

typedef _Float16 half8 __attribute__((ext_vector_type(8)));
typedef float   float4v __attribute__((ext_vector_type(4)));

static __device__ __forceinline__ float4v mfma16(half8 a, half8 b, float4v c) {
    return __builtin_amdgcn_mfma_f32_16x16x32_f16(a, b, c, 0, 0, 0);
}
static __device__ __forceinline__ float sigm(float x) { return 1.f / (1.f + __expf(-x)); }

// ---------------- K1: EWi'[v][c] = (v==0 ? 0 : embed[v]@Wi[:,c]) + bi[c] ----------------
__global__ __launch_bounds__(640) void ewi_kernel(const float* __restrict__ embed,
                                                  const float* __restrict__ Wi,
                                                  const float* __restrict__ bi,
                                                  float* __restrict__ EWi) {
    __shared__ __align__(16) float emb_s[32][EE];
    const int i0  = blockIdx.x * 32;
    const int tid = threadIdx.x;
    for (int idx = tid; idx < 32 * EE; idx += 640) {
        int r = idx / EE, e = idx % EE;
        int gr = i0 + r;
        emb_s[r][e] = (gr < NI) ? embed[(size_t)gr * EE + e] : 0.f;
    }
    __syncthreads();
    const int j = tid;
    if (j < GG) {
        float acc[32];
        #pragma unroll
        for (int r = 0; r < 32; ++r) acc[r] = 0.f;
        for (int e = 0; e < EE; ++e) {
            float w = Wi[(size_t)e * GG + j];
            #pragma unroll
            for (int r = 0; r < 32; ++r) acc[r] += emb_s[r][e] * w;
        }
        const float bij = bi[j];
        int rmax = (NI - i0) < 32 ? (NI - i0) : 32;
        for (int r = 0; r < rmax; ++r) {
            float v = (i0 + r == 0) ? 0.f : acc[r];
            EWi[(size_t)(i0 + r) * GG + j] = v + bij;
        }
    }
}

// ---------------- K1b: repack Wh -> f16 MFMA B-fragments ----------------
// Whf[((g*16+tc)*7+kt)*64 + lane] = half8 of B[k][n]: n = tc*16+(lane&15) within gate,
// k = kt*32 + (lane>>4)*8 + j. Zero-padded outside 200x200 per gate.
__global__ __launch_bounds__(64) void repack_whf(const float* __restrict__ Wh,
                                                 half8* __restrict__ Whf) {
    const int bx   = blockIdx.x;        // tile*7 + kt, tile = g*16+tc
    const int kt   = bx % NKT;
    const int tile = bx / NKT;
    const int g    = tile / 16;
    const int tc   = tile % 16;
    const int lane = threadIdx.x;
    const int col  = tc * 16 + (lane & 15);
    half8 v;
    #pragma unroll
    for (int j = 0; j < 8; ++j) {
        int k = kt * 32 + (lane >> 4) * 8 + j;
        float w = (k < HH && col < HH) ? Wh[(size_t)k * GG + g * HH + col] : 0.f;
        v[j] = (_Float16)w;
    }
    Whf[(size_t)bx * 64 + lane] = v;
}

// ---------------- K2: weight-stationary MFMA GRU scan ----------------
// 256 blocks x 512 threads (8 waves, 2/SIMD). 4 batch rows/block (M=16 MFMA, rows 4-15 zero).
// Wave w owns tile-cols {w, w+8} for ALL 3 gates -> 42 register-resident B-frags.
// h: LDS double-buffer [16][HSTR] f16; h_old in registers; 1 barrier/step.
__global__ __launch_bounds__(512, 2) void scan_mfma(const int* __restrict__ q,
                                                    const float* __restrict__ EWi,
                                                    const half8* __restrict__ Whf,
                                                    const float* __restrict__ bhn,
                                                    _Float16* __restrict__ h16g) {
    __shared__ __align__(16) _Float16 hbuf[2][16 * HSTR];

    const int tid  = threadIdx.x;
    const int w    = tid >> 6;
    const int lane = tid & 63;
    const int l15  = lane & 15;
    const int lhi  = lane >> 4;
    const int b0   = blockIdx.x * 4;
    const bool lo16 = (lane < 16);

    for (int idx = tid; idx < 2 * 16 * HSTR; idx += 512)
        ((_Float16*)hbuf)[idx] = (_Float16)0.f;

    // --- register-resident Wh fragments: [gate][c2][kt] ---
    half8 wb[3][2][7];
    #pragma unroll
    for (int g = 0; g < 3; ++g) {
        #pragma unroll
        for (int c2 = 0; c2 < 2; ++c2) {
            const int tc = w + c2 * 8;
            #pragma unroll
            for (int kt = 0; kt < NKT; ++kt)
                wb[g][c2][kt] = Whf[((size_t)(g * 16 + tc) * NKT + kt) * 64 + lane];
        }
    }

    const int col0 = w * 16 + l15;            // always < 128 < 200
    const int col1 = (w + 8) * 16 + l15;      // 128..255, valid if < 200
    const bool v1  = lo16 && (col1 < HH);
    const float bhn0 = lo16 ? bhn[col0] : 0.f;
    const float bhn1 = v1   ? bhn[col1] : 0.f;

    float hreg[2][4];
    #pragma unroll
    for (int c2 = 0; c2 < 2; ++c2)
        #pragma unroll
        for (int b = 0; b < 4; ++b) hreg[c2][b] = 0.f;

    __syncthreads();

    int cur = 0;
    for (int t = 0; t < TT; ++t) {
        // ---- gi gather (issued early; only lanes 0-15 load) ----
        float gi[3][2][4];
        #pragma unroll
        for (int b = 0; b < 4; ++b) {
            const int qv = q[(size_t)(b0 + b) * TT + t];
            const float* ew = EWi + (size_t)qv * GG;
            #pragma unroll
            for (int g = 0; g < 3; ++g) {
                gi[g][0][b] = lo16 ? ew[g * HH + col0] : 0.f;
                gi[g][1][b] = v1   ? ew[g * HH + col1] : 0.f;
            }
        }

        // ---- gh = h @ Wh via MFMA, Wh stationary ----
        float4v acc[3][2];
        #pragma unroll
        for (int g = 0; g < 3; ++g)
            #pragma unroll
            for (int c2 = 0; c2 < 2; ++c2)
                acc[g][c2] = (float4v){0.f, 0.f, 0.f, 0.f};

        const _Float16* hb = &hbuf[cur][0];
        #pragma unroll
        for (int kt = 0; kt < NKT; ++kt) {
            const half8 af = *(const half8*)(hb + l15 * HSTR + kt * 32 + lhi * 8);
            #pragma unroll
            for (int g = 0; g < 3; ++g) {
                acc[g][0] = mfma16(af, wb[g][0][kt], acc[g][0]);
                acc[g][1] = mfma16(af, wb[g][1][kt], acc[g][1]);
            }
        }

        // ---- combine (lanes 0-15 hold C rows 0-3 = the 4 real batch rows) ----
        _Float16* hn = &hbuf[cur ^ 1][0];
        if (lo16) {
            #pragma unroll
            for (int b = 0; b < 4; ++b) {
                float r = sigm(gi[0][0][b] + acc[0][0][b]);
                float z = sigm(gi[1][0][b] + acc[1][0][b]);
                float n = tanhf(gi[2][0][b] + r * (acc[2][0][b] + bhn0));
                float hv = (1.f - z) * n + z * hreg[0][b];
                hreg[0][b] = hv;
                hn[b * HSTR + col0] = (_Float16)hv;
            }
            if (v1) {
                #pragma unroll
                for (int b = 0; b < 4; ++b) {
                    float r = sigm(gi[0][1][b] + acc[0][1][b]);
                    float z = sigm(gi[1][1][b] + acc[1][1][b]);
                    float n = tanhf(gi[2][1][b] + r * (acc[2][1][b] + bhn1));
                    float hv = (1.f - z) * n + z * hreg[1][b];
                    hreg[1][b] = hv;
                    hn[b * HSTR + col1] = (_Float16)hv;
                }
            }
        }
        __syncthreads();
        cur ^= 1;
    }

    // ---- export h_last as f16 [1024][224] (k 200..223 are zeros from init) ----
    for (int idx = tid; idx < 4 * KPAD; idx += 512) {
        int b = idx / KPAD, k = idx % KPAD;
        h16g[(size_t)(b0 + b) * KPAD + k] = hbuf[cur][b * HSTR + k];
    }
}

// ---------------- K3: out = h_last @ Wo + bo via f16 MFMA ----------------
// Block = 4 waves x 1 n-tile (16 cols); wave loops all 64 m-tiles with Wo
// fragments register-resident (each Wo column read exactly once from HBM).
__global__ __launch_bounds__(256) void out_mfma(const _Float16* __restrict__ h16g,
                                                const float* __restrict__ Wo,
                                                const float* __restrict__ bo,
                                                float* __restrict__ out) {
    const int tid  = threadIdx.x;
    const int w    = tid >> 6;
    const int lane = tid & 63;
    const int l15  = lane & 15;
    const int lhi  = lane >> 4;

    const int nt   = blockIdx.x * 4 + w;
    const bool live = (nt < NTILE3);
    const int ntc  = live ? nt : (NTILE3 - 1);
    const int col  = ntc * 16 + l15;

    // B-frags: convert Wo column slices to f16 in-register (read once per column)
    half8 wb[7];
    #pragma unroll
    for (int kt = 0; kt < NKT; ++kt) {
        #pragma unroll
        for (int j = 0; j < 8; ++j) {
            int k = kt * 32 + lhi * 8 + j;
            wb[kt][j] = (k < HH) ? (_Float16)Wo[(size_t)k * NI + col] : (_Float16)0.f;
        }
    }
    const float bov = bo[col];

    for (int mt = 0; mt < BATCH / 16; ++mt) {
        const _Float16* hrow = h16g + (size_t)(mt * 16 + l15) * KPAD + lhi * 8;
        float4v acc = (float4v){0.f, 0.f, 0.f, 0.f};
        #pragma unroll
        for (int kt = 0; kt < NKT; ++kt) {
            const half8 af = *(const half8*)(hrow + kt * 32);
            acc = mfma16(af, wb[kt], acc);
        }
        if (live) {
            #pragma unroll
            for (int r = 0; r < 4; ++r) {
                int row = mt * 16 + lhi * 4 + r;
                out[(size_t)row * NI + col] = acc[r] + bov;
            }
        }
    }
}

extern "C" void kernel_launch(void* const* d_in, const int* in_sizes, int n_in,
                              void* d_out, int out_size, void* d_ws, size_t ws_size,
                              hipStream_t stream) {
    const int*   q     = (const int*)d_in[0];
    const float* embed = (const float*)d_in[1];
    const float* Wi    = (const float*)d_in[2];
    const float* bi    = (const float*)d_in[3];
    const float* Wh    = (const float*)d_in[4];
    const float* bhn   = (const float*)d_in[5];
    const float* Wo    = (const float*)d_in[6];
    const float* bo    = (const float*)d_in[7];
    float* out = (float*)d_out;

    // Scratch layout:
    //   EWi [50000 x 600] f32 = 120,000,000 B at d_out+0     (read only by scan)
    //   Whf [48*7 frags]  f16 =     344,064 B at d_out+120M  (read only by scan)
    //   (K3 overwrites d_out AFTER scan completes - stream-ordered, safe)
    //   h16g [1024 x 224] f16 = 458,752 B in d_ws
    float*    EWi  = out;
    half8*    Whf  = (half8*)((char*)d_out + 120000000);
    _Float16* h16g = (_Float16*)d_ws;

    ewi_kernel<<<(NI + 31) / 32, 640, 0, stream>>>(embed, Wi, bi, EWi);
    repack_whf<<<48 * NKT, 64, 0, stream>>>(Wh, Whf);
    scan_mfma<<<BATCH / 4, 512, 0, stream>>>(q, EWi, Whf, bhn, h16g);
    out_mfma<<<(NTILE3 + 3) / 4, 256, 0, stream>>>(h16g, Wo, bo, out);
}

// Round 5
// 751.688 us; speedup vs baseline: 16.9918x; 1.1399x over previous
//
#include <hip/hip_runtime.h>

#define BATCH 1024
#define TT    200
#define EE    100
#define HH    200
#define GG    600   // 3*HH
#define NI    50000
#define NKT   7     // k-tiles: 224 = 7*32 (K=200 padded)
#define KPAD  224
#define HSTR  232   // LDS row stride in f16 (464 B = 29*16B)
#define NTILE3 3125 // 50000/16 output n-tiles

typedef _Float16 half8 __attribute__((ext_vector_type(8)));
typedef float   float4v __attribute__((ext_vector_type(4)));

static __device__ __forceinline__ float4v mfma16(half8 a, half8 b, float4v c) {
    return __builtin_amdgcn_mfma_f32_16x16x32_f16(a, b, c, 0, 0, 0);
}

#if __has_builtin(__builtin_amdgcn_rcpf)
static __device__ __forceinline__ float fastrcp(float x) { return __builtin_amdgcn_rcpf(x); }
#else
static __device__ __forceinline__ float fastrcp(float x) { return 1.f / x; }
#endif

// sigmoid: 1/(1+e^-x); saturates correctly (e^-x -> inf -> 0, -> 0 -> 1)
static __device__ __forceinline__ float sigm(float x) {
    return fastrcp(1.f + __expf(-x));
}
// tanh via exp, branch-free, saturates correctly for large |x|
static __device__ __forceinline__ float tanh_fast(float x) {
    float e = __expf(2.f * fabsf(x));          // inf ok
    float t = 1.f - 2.f * fastrcp(e + 1.f);
    return __builtin_copysignf(t, x);
}

// ---------------- K1: EWi'[v][c] = (v==0 ? 0 : embed[v]@Wi[:,c]) + bi[c] ----------------
__global__ __launch_bounds__(640) void ewi_kernel(const float* __restrict__ embed,
                                                  const float* __restrict__ Wi,
                                                  const float* __restrict__ bi,
                                                  float* __restrict__ EWi) {
    __shared__ __align__(16) float emb_s[32][EE];
    const int i0  = blockIdx.x * 32;
    const int tid = threadIdx.x;
    for (int idx = tid; idx < 32 * EE; idx += 640) {
        int r = idx / EE, e = idx % EE;
        int gr = i0 + r;
        emb_s[r][e] = (gr < NI) ? embed[(size_t)gr * EE + e] : 0.f;
    }
    __syncthreads();
    const int j = tid;
    if (j < GG) {
        float acc[32];
        #pragma unroll
        for (int r = 0; r < 32; ++r) acc[r] = 0.f;
        for (int e = 0; e < EE; ++e) {
            float w = Wi[(size_t)e * GG + j];
            #pragma unroll
            for (int r = 0; r < 32; ++r) acc[r] += emb_s[r][e] * w;
        }
        const float bij = bi[j];
        int rmax = (NI - i0) < 32 ? (NI - i0) : 32;
        for (int r = 0; r < rmax; ++r) {
            float v = (i0 + r == 0) ? 0.f : acc[r];
            EWi[(size_t)(i0 + r) * GG + j] = v + bij;
        }
    }
}

// ---------------- K1b: repack Wh -> f16 MFMA B-fragments ----------------
__global__ __launch_bounds__(64) void repack_whf(const float* __restrict__ Wh,
                                                 half8* __restrict__ Whf) {
    const int bx   = blockIdx.x;        // tile*7 + kt, tile = g*16+tc
    const int kt   = bx % NKT;
    const int tile = bx / NKT;
    const int g    = tile / 16;
    const int tc   = tile % 16;
    const int lane = threadIdx.x;
    const int col  = tc * 16 + (lane & 15);
    half8 v;
    #pragma unroll
    for (int j = 0; j < 8; ++j) {
        int k = kt * 32 + (lane >> 4) * 8 + j;
        float w = (k < HH && col < HH) ? Wh[(size_t)k * GG + g * HH + col] : 0.f;
        v[j] = (_Float16)w;
    }
    Whf[(size_t)bx * 64 + lane] = v;
}

// ---------------- K2: weight-stationary MFMA GRU scan ----------------
// 256 blocks x 512 threads (8 waves, 2/SIMD). 4 batch rows/block (M=16, rows 4-15 zero).
// Wave w owns tile-cols {w, w+8} for all 3 gates -> 42 register/AGPR-resident B-frags
// (register file is ~full at 2 waves/SIMD: no extra live arrays allowed).
// Round-5: fast activations (tanhf was ~half the step's VALU), q preloaded to LDS,
// gi gather rotated to after combine (loads fly across the barrier, covered by
// the next step's MFMA phase, zero extra registers).
__global__ __launch_bounds__(512, 2) void scan_mfma(const int* __restrict__ q,
                                                    const float* __restrict__ EWi,
                                                    const half8* __restrict__ Whf,
                                                    const float* __restrict__ bhn,
                                                    _Float16* __restrict__ h16g) {
    __shared__ __align__(16) _Float16 hbuf[2][16 * HSTR];
    __shared__ int qs[4][TT];

    const int tid  = threadIdx.x;
    const int w    = tid >> 6;
    const int lane = tid & 63;
    const int l15  = lane & 15;
    const int lhi  = lane >> 4;
    const int b0   = blockIdx.x * 4;
    const bool lo16 = (lane < 16);

    for (int idx = tid; idx < 2 * 16 * HSTR; idx += 512)
        ((_Float16*)hbuf)[idx] = (_Float16)0.f;
    for (int idx = tid; idx < 4 * TT; idx += 512) {
        int b = idx / TT, t = idx % TT;
        qs[b][t] = q[(size_t)(b0 + b) * TT + t];
    }

    // --- register-resident Wh fragments: [gate][c2][kt] ---
    half8 wb[3][2][7];
    #pragma unroll
    for (int g = 0; g < 3; ++g) {
        #pragma unroll
        for (int c2 = 0; c2 < 2; ++c2) {
            const int tc = w + c2 * 8;
            #pragma unroll
            for (int kt = 0; kt < NKT; ++kt)
                wb[g][c2][kt] = Whf[((size_t)(g * 16 + tc) * NKT + kt) * 64 + lane];
        }
    }

    const int col0 = w * 16 + l15;            // < 128 < 200 always
    const int col1 = (w + 8) * 16 + l15;      // 128..255, valid if < 200
    const bool v1  = lo16 && (col1 < HH);
    const float bhn0 = lo16 ? bhn[col0] : 0.f;
    const float bhn1 = v1   ? bhn[col1] : 0.f;

    float hreg[2][4];
    #pragma unroll
    for (int c2 = 0; c2 < 2; ++c2)
        #pragma unroll
        for (int b = 0; b < 4; ++b) hreg[c2][b] = 0.f;

    __syncthreads();

    // gi gather (32-bit indexing; only lanes 0-15 issue loads)
    float gi[3][2][4];
    #define LOADGI(tt) do {                                               \
        _Pragma("unroll")                                                 \
        for (int b = 0; b < 4; ++b) {                                     \
            const int base = qs[b][tt] * GG;                              \
            const float* __restrict__ ew = EWi + base;                    \
            _Pragma("unroll")                                             \
            for (int g = 0; g < 3; ++g) {                                 \
                gi[g][0][b] = lo16 ? ew[g * HH + col0] : 0.f;             \
                gi[g][1][b] = v1   ? ew[g * HH + col1] : 0.f;             \
            }                                                             \
        }                                                                 \
    } while (0)

    LOADGI(0);

    int cur = 0;
    for (int t = 0; t < TT; ++t) {
        // ---- gh = h @ Wh via MFMA, Wh stationary ----
        float4v acc[3][2];
        #pragma unroll
        for (int g = 0; g < 3; ++g)
            #pragma unroll
            for (int c2 = 0; c2 < 2; ++c2)
                acc[g][c2] = (float4v){0.f, 0.f, 0.f, 0.f};

        const _Float16* hb = &hbuf[cur][0];
        #pragma unroll
        for (int kt = 0; kt < NKT; ++kt) {
            const half8 af = *(const half8*)(hb + l15 * HSTR + kt * 32 + lhi * 8);
            #pragma unroll
            for (int g = 0; g < 3; ++g) {
                acc[g][0] = mfma16(af, wb[g][0][kt], acc[g][0]);
                acc[g][1] = mfma16(af, wb[g][1][kt], acc[g][1]);
            }
        }

        // ---- combine (lanes 0-15 hold C rows 0-3 = the 4 real batch rows) ----
        _Float16* hn = &hbuf[cur ^ 1][0];
        if (lo16) {
            #pragma unroll
            for (int b = 0; b < 4; ++b) {
                float r = sigm(gi[0][0][b] + acc[0][0][b]);
                float z = sigm(gi[1][0][b] + acc[1][0][b]);
                float n = tanh_fast(gi[2][0][b] + r * (acc[2][0][b] + bhn0));
                float hv = (1.f - z) * n + z * hreg[0][b];
                hreg[0][b] = hv;
                hn[b * HSTR + col0] = (_Float16)hv;
            }
            if (v1) {
                #pragma unroll
                for (int b = 0; b < 4; ++b) {
                    float r = sigm(gi[0][1][b] + acc[0][1][b]);
                    float z = sigm(gi[1][1][b] + acc[1][1][b]);
                    float n = tanh_fast(gi[2][1][b] + r * (acc[2][1][b] + bhn1));
                    float hv = (1.f - z) * n + z * hreg[1][b];
                    hreg[1][b] = hv;
                    hn[b * HSTR + col1] = (_Float16)hv;
                }
            }
        }

        // ---- prefetch next step's gi: in flight across the barrier,
        //      covered by next step's MFMA phase ----
        const int tn = (t + 1 < TT) ? (t + 1) : t;
        LOADGI(tn);

        __syncthreads();
        cur ^= 1;
    }

    // ---- export h_last as f16 [1024][224] (k 200..223 zeros from init) ----
    for (int idx = tid; idx < 4 * KPAD; idx += 512) {
        int b = idx / KPAD, k = idx % KPAD;
        h16g[(size_t)(b0 + b) * KPAD + k] = hbuf[cur][b * HSTR + k];
    }
    #undef LOADGI
}

// ---------------- K3: out = h_last @ Wo + bo via f16 MFMA ----------------
__global__ __launch_bounds__(256) void out_mfma(const _Float16* __restrict__ h16g,
                                                const float* __restrict__ Wo,
                                                const float* __restrict__ bo,
                                                float* __restrict__ out) {
    const int tid  = threadIdx.x;
    const int w    = tid >> 6;
    const int lane = tid & 63;
    const int l15  = lane & 15;
    const int lhi  = lane >> 4;

    const int nt   = blockIdx.x * 4 + w;
    const bool live = (nt < NTILE3);
    const int ntc  = live ? nt : (NTILE3 - 1);
    const int col  = ntc * 16 + l15;

    half8 wb[7];
    #pragma unroll
    for (int kt = 0; kt < NKT; ++kt) {
        #pragma unroll
        for (int j = 0; j < 8; ++j) {
            int k = kt * 32 + lhi * 8 + j;
            wb[kt][j] = (k < HH) ? (_Float16)Wo[(size_t)k * NI + col] : (_Float16)0.f;
        }
    }
    const float bov = bo[col];

    for (int mt = 0; mt < BATCH / 16; ++mt) {
        const _Float16* hrow = h16g + (size_t)(mt * 16 + l15) * KPAD + lhi * 8;
        float4v acc = (float4v){0.f, 0.f, 0.f, 0.f};
        #pragma unroll
        for (int kt = 0; kt < NKT; ++kt) {
            const half8 af = *(const half8*)(hrow + kt * 32);
            acc = mfma16(af, wb[kt], acc);
        }
        if (live) {
            #pragma unroll
            for (int r = 0; r < 4; ++r) {
                int row = mt * 16 + lhi * 4 + r;
                out[(size_t)row * NI + col] = acc[r] + bov;
            }
        }
    }
}

extern "C" void kernel_launch(void* const* d_in, const int* in_sizes, int n_in,
                              void* d_out, int out_size, void* d_ws, size_t ws_size,
                              hipStream_t stream) {
    const int*   q     = (const int*)d_in[0];
    const float* embed = (const float*)d_in[1];
    const float* Wi    = (const float*)d_in[2];
    const float* bi    = (const float*)d_in[3];
    const float* Wh    = (const float*)d_in[4];
    const float* bhn   = (const float*)d_in[5];
    const float* Wo    = (const float*)d_in[6];
    const float* bo    = (const float*)d_in[7];
    float* out = (float*)d_out;

    // Scratch layout:
    //   EWi [50000 x 600] f32 = 120,000,000 B at d_out+0     (read only by scan)
    //   Whf [48*7 frags]  f16 =     344,064 B at d_out+120M  (read only by scan)
    //   (K3 overwrites d_out AFTER scan completes - stream-ordered, safe)
    //   h16g [1024 x 224] f16 = 458,752 B in d_ws
    float*    EWi  = out;
    half8*    Whf  = (half8*)((char*)d_out + 120000000);
    _Float16* h16g = (_Float16*)d_ws;

    ewi_kernel<<<(NI + 31) / 32, 640, 0, stream>>>(embed, Wi, bi, EWi);
    repack_whf<<<48 * NKT, 64, 0, stream>>>(Wh, Whf);
    scan_mfma<<<BATCH / 4, 512, 0, stream>>>(q, EWi, Whf, bhn, h16g);
    out_mfma<<<(NTILE3 + 3) / 4, 256, 0, stream>>>(h16g, Wo, bo, out);
}

// Round 6
// 586.252 us; speedup vs baseline: 21.7868x; 1.2822x over previous
//
#include <hip/hip_runtime.h>

#define BATCH 1024
#define TT    200
#define EE    100
#define HH    200
#define GG    600   // 3*HH
#define NI    50000
#define NKT   7     // k-tiles: 224 = 7*32 (K=200 padded)
#define KPAD  224
#define HSTR  264   // LDS h row stride in f16 (dump zone 232+, pad zone 200-231 stays 0)
#define NTILE3 3125 // 50000/16 output n-tiles

typedef _Float16 half8 __attribute__((ext_vector_type(8)));
typedef _Float16 half4v __attribute__((ext_vector_type(4)));
typedef float   float4v __attribute__((ext_vector_type(4)));

static __device__ __forceinline__ float4v mfma16(half8 a, half8 b, float4v c) {
    return __builtin_amdgcn_mfma_f32_16x16x32_f16(a, b, c, 0, 0, 0);
}

#if __has_builtin(__builtin_amdgcn_rcpf)
static __device__ __forceinline__ float fastrcp(float x) { return __builtin_amdgcn_rcpf(x); }
#else
static __device__ __forceinline__ float fastrcp(float x) { return 1.f / x; }
#endif

static __device__ __forceinline__ float sigm(float x) {
    return fastrcp(1.f + __expf(-x));
}
static __device__ __forceinline__ float tanh_fast(float x) {
    float e = __expf(2.f * fabsf(x));
    float t = 1.f - 2.f * fastrcp(e + 1.f);
    return __builtin_copysignf(t, x);
}

// ---------------- K1: EWi16[v][c][g] = ((v==0?0:embed[v]@Wi[:,g*200+c]) + bi)  (f16, padded x4) ----------------
__global__ __launch_bounds__(640) void ewi_kernel(const float* __restrict__ embed,
                                                  const float* __restrict__ Wi,
                                                  const float* __restrict__ bi,
                                                  _Float16* __restrict__ EWi16) {
    __shared__ __align__(16) float emb_s[32][EE];
    const int i0  = blockIdx.x * 32;
    const int tid = threadIdx.x;
    for (int idx = tid; idx < 32 * EE; idx += 640) {
        int r = idx / EE, e = idx % EE;
        int gr = i0 + r;
        emb_s[r][e] = (gr < NI) ? embed[(size_t)gr * EE + e] : 0.f;
    }
    __syncthreads();
    const int j = tid;
    if (j < GG) {
        const int g = j / HH, c = j % HH;
        float acc[32];
        #pragma unroll
        for (int r = 0; r < 32; ++r) acc[r] = 0.f;
        for (int e = 0; e < EE; ++e) {
            float w = Wi[(size_t)e * GG + j];
            #pragma unroll
            for (int r = 0; r < 32; ++r) acc[r] += emb_s[r][e] * w;
        }
        const float bij = bi[j];
        int rmax = (NI - i0) < 32 ? (NI - i0) : 32;
        for (int r = 0; r < rmax; ++r) {
            float v = (i0 + r == 0) ? 0.f : acc[r];
            EWi16[(size_t)(i0 + r) * 800 + c * 4 + g] = (_Float16)(v + bij);
        }
    }
}

// ---------------- K1b: repack Wh -> f16 MFMA B-fragments ----------------
__global__ __launch_bounds__(64) void repack_whf(const float* __restrict__ Wh,
                                                 half8* __restrict__ Whf) {
    const int bx   = blockIdx.x;        // tile*7 + kt, tile = g*16+tc
    const int kt   = bx % NKT;
    const int tile = bx / NKT;
    const int g    = tile / 16;
    const int tc   = tile % 16;
    const int lane = threadIdx.x;
    const int col  = tc * 16 + (lane & 15);
    half8 v;
    #pragma unroll
    for (int j = 0; j < 8; ++j) {
        int k = kt * 32 + (lane >> 4) * 8 + j;
        float w = (k < HH && col < HH) ? Wh[(size_t)k * GG + g * HH + col] : 0.f;
        v[j] = (_Float16)w;
    }
    Whf[(size_t)bx * 64 + lane] = v;
}

// ---------------- K2: weight-stationary MFMA GRU scan, dense combine ----------------
// 256 blocks x 512 threads. Wave w owns tile-cols {w, w+8} x 3 gates (42 B-frags stationary).
// After MFMA: lanes 0-15 stage C-frags to accbuf (same-wave LDS, no barrier); ALL 64 lanes
// then combine one (b=lane>>4, col=lane&15) pair per c2 -> 4x lane density vs round 5.
// gi: packed-f16 EWi rows -> 2 unmasked 8B loads/lane, prefetched 2 steps ahead.
__global__ __launch_bounds__(512, 2) void scan_mfma(const int* __restrict__ q,
                                                    const _Float16* __restrict__ EWi16,
                                                    const half8* __restrict__ Whf,
                                                    const float* __restrict__ bhn,
                                                    _Float16* __restrict__ h16g) {
    __shared__ __align__(16) _Float16 hbuf[2][16 * HSTR];
    __shared__ __align__(16) float accbuf[48 * 16 * 4];   // [tilegate][col15][b]
    __shared__ int qs[4][TT];

    const int tid  = threadIdx.x;
    const int w    = tid >> 6;
    const int lane = tid & 63;
    const int l15  = lane & 15;
    const int lhi  = lane >> 4;     // = batch row b in combine
    const int b0   = blockIdx.x * 4;

    for (int idx = tid; idx < 2 * 16 * HSTR; idx += 512)
        ((_Float16*)hbuf)[idx] = (_Float16)0.f;
    for (int idx = tid; idx < 4 * TT; idx += 512) {
        int b = idx / TT, t = idx % TT;
        qs[b][t] = q[(size_t)(b0 + b) * TT + t];
    }

    // --- register-resident Wh fragments: [gate][c2][kt] ---
    half8 wb[3][2][7];
    #pragma unroll
    for (int g = 0; g < 3; ++g) {
        #pragma unroll
        for (int c2 = 0; c2 < 2; ++c2) {
            const int tc = w + c2 * 8;
            #pragma unroll
            for (int kt = 0; kt < NKT; ++kt)
                wb[g][c2][kt] = Whf[((size_t)(g * 16 + tc) * NKT + kt) * 64 + lane];
        }
    }

    const int col0 = w * 16 + l15;            // 0..127, always valid
    const int col1 = 128 + w * 16 + l15;      // 128..255, valid iff < 200
    const bool v1  = (col1 < HH);
    const int colw1 = v1 ? col1 : 236;        // dump slot (never read/exported)
    const float bh0 = bhn[col0];
    const float bh1 = v1 ? bhn[col1] : 0.f;

    float hreg0 = 0.f, hreg1 = 0.f;           // h_old for (b=lhi, col0/col1)

    __syncthreads();

    half4v giA0, giA1, giB0, giB1;
    #define LOADGI(d0, d1, tt) do {                                          \
        const int qv = qs[lhi][tt];                                          \
        const _Float16* ew = EWi16 + (size_t)qv * 800;                       \
        d0 = *(const half4v*)(ew + col0 * 4);                                \
        d1 = *(const half4v*)(ew + col1 * 4);                                \
    } while (0)

    LOADGI(giA0, giA1, 0);
    LOADGI(giB0, giB1, 1);

    #define STEP(CUR, NXT, G0, G1, TLOAD) do {                               \
        float4v acc[3][2];                                                   \
        _Pragma("unroll")                                                    \
        for (int g = 0; g < 3; ++g)                                          \
            _Pragma("unroll")                                                \
            for (int c2 = 0; c2 < 2; ++c2)                                   \
                acc[g][c2] = (float4v){0.f, 0.f, 0.f, 0.f};                  \
        const _Float16* hb = &hbuf[CUR][0];                                  \
        _Pragma("unroll")                                                    \
        for (int kt = 0; kt < NKT; ++kt) {                                   \
            const half8 af = *(const half8*)(hb + l15 * HSTR + kt * 32 + lhi * 8); \
            _Pragma("unroll")                                                \
            for (int g = 0; g < 3; ++g) {                                    \
                acc[g][0] = mfma16(af, wb[g][0][kt], acc[g][0]);             \
                acc[g][1] = mfma16(af, wb[g][1][kt], acc[g][1]);             \
            }                                                                \
        }                                                                    \
        /* redistribute: lanes 0-15 hold rows 0-3 (the real batch) */        \
        if (lane < 16) {                                                     \
            _Pragma("unroll")                                                \
            for (int g = 0; g < 3; ++g)                                      \
                _Pragma("unroll")                                            \
                for (int c2 = 0; c2 < 2; ++c2)                               \
                    *(float4v*)&accbuf[(((g * 16) + w + c2 * 8) * 16 + l15) * 4] = acc[g][c2]; \
        }                                                                    \
        /* dense combine: lane -> (b=lhi, col0|col1) */                      \
        _Float16* hn = &hbuf[NXT][0];                                        \
        {                                                                    \
            const int base0 = ((w) * 16 + l15) * 4 + lhi;                    \
            const int base1 = ((w + 8) * 16 + l15) * 4 + lhi;                \
            float aR0 = accbuf[0 * 1024 + base0];                            \
            float aZ0 = accbuf[1 * 1024 + base0];                            \
            float aN0 = accbuf[2 * 1024 + base0];                            \
            float aR1 = accbuf[0 * 1024 + base1];                            \
            float aZ1 = accbuf[1 * 1024 + base1];                            \
            float aN1 = accbuf[2 * 1024 + base1];                            \
            float r0 = sigm((float)G0[0] + aR0);                             \
            float z0 = sigm((float)G0[1] + aZ0);                             \
            float n0 = tanh_fast((float)G0[2] + r0 * (aN0 + bh0));           \
            float hv0 = (1.f - z0) * n0 + z0 * hreg0;                        \
            hreg0 = hv0;                                                     \
            hn[lhi * HSTR + col0] = (_Float16)hv0;                           \
            float r1 = sigm((float)G1[0] + aR1);                             \
            float z1 = sigm((float)G1[1] + aZ1);                             \
            float n1 = tanh_fast((float)G1[2] + r1 * (aN1 + bh1));           \
            float hv1 = (1.f - z1) * n1 + z1 * hreg1;                        \
            hreg1 = hv1;                                                     \
            hn[lhi * HSTR + colw1] = (_Float16)hv1;                          \
        }                                                                    \
        /* prefetch gi two steps ahead (overwrites the set just consumed) */ \
        {                                                                    \
            const int tl = (TLOAD) < TT ? (TLOAD) : (TT - 1);                \
            LOADGI(G0, G1, tl);                                              \
        }                                                                    \
        __syncthreads();                                                     \
    } while (0)

    for (int t = 0; t < TT; t += 2) {
        STEP(0, 1, giA0, giA1, t + 2);
        STEP(1, 0, giB0, giB1, t + 3);
    }
    #undef STEP
    #undef LOADGI

    // ---- export h_last (rows 0-3; k 200..223 are zeros from init) ----
    for (int idx = tid; idx < 4 * KPAD; idx += 512) {
        int b = idx / KPAD, k = idx % KPAD;
        h16g[(size_t)(b0 + b) * KPAD + k] = hbuf[0][b * HSTR + k];
    }
}

// ---------------- K3: out = h_last @ Wo + bo via f16 MFMA ----------------
__global__ __launch_bounds__(256) void out_mfma(const _Float16* __restrict__ h16g,
                                                const float* __restrict__ Wo,
                                                const float* __restrict__ bo,
                                                float* __restrict__ out) {
    const int tid  = threadIdx.x;
    const int w    = tid >> 6;
    const int lane = tid & 63;
    const int l15  = lane & 15;
    const int lhi  = lane >> 4;

    const int nt   = blockIdx.x * 4 + w;
    const bool live = (nt < NTILE3);
    const int ntc  = live ? nt : (NTILE3 - 1);
    const int col  = ntc * 16 + l15;

    half8 wb[7];
    #pragma unroll
    for (int kt = 0; kt < NKT; ++kt) {
        #pragma unroll
        for (int j = 0; j < 8; ++j) {
            int k = kt * 32 + lhi * 8 + j;
            wb[kt][j] = (k < HH) ? (_Float16)Wo[(size_t)k * NI + col] : (_Float16)0.f;
        }
    }
    const float bov = bo[col];

    for (int mt = 0; mt < BATCH / 16; ++mt) {
        const _Float16* hrow = h16g + (size_t)(mt * 16 + l15) * KPAD + lhi * 8;
        float4v acc = (float4v){0.f, 0.f, 0.f, 0.f};
        #pragma unroll
        for (int kt = 0; kt < NKT; ++kt) {
            const half8 af = *(const half8*)(hrow + kt * 32);
            acc = mfma16(af, wb[kt], acc);
        }
        if (live) {
            #pragma unroll
            for (int r = 0; r < 4; ++r) {
                int row = mt * 16 + lhi * 4 + r;
                out[(size_t)row * NI + col] = acc[r] + bov;
            }
        }
    }
}

extern "C" void kernel_launch(void* const* d_in, const int* in_sizes, int n_in,
                              void* d_out, int out_size, void* d_ws, size_t ws_size,
                              hipStream_t stream) {
    const int*   q     = (const int*)d_in[0];
    const float* embed = (const float*)d_in[1];
    const float* Wi    = (const float*)d_in[2];
    const float* bi    = (const float*)d_in[3];
    const float* Wh    = (const float*)d_in[4];
    const float* bhn   = (const float*)d_in[5];
    const float* Wo    = (const float*)d_in[6];
    const float* bo    = (const float*)d_in[7];
    float* out = (float*)d_out;

    // Scratch layout in d_out (204.8 MB), consumed before K3 overwrites it:
    //   EWi16 [50000 x 200 x 4] f16 = 80,000,000 B at +0
    //   Whf   [48*7 frags]      f16 =    344,064 B at +120,000,000
    //   h16g  [1024 x 224] f16 = 458,752 B in d_ws
    _Float16* EWi16 = (_Float16*)d_out;
    half8*    Whf   = (half8*)((char*)d_out + 120000000);
    _Float16* h16g  = (_Float16*)d_ws;

    ewi_kernel<<<(NI + 31) / 32, 640, 0, stream>>>(embed, Wi, bi, EWi16);
    repack_whf<<<48 * NKT, 64, 0, stream>>>(Wh, Whf);
    scan_mfma<<<BATCH / 4, 512, 0, stream>>>(q, EWi16, Whf, bhn, h16g);
    out_mfma<<<(NTILE3 + 3) / 4, 256, 0, stream>>>(h16g, Wo, bo, out);
}

// Round 7
// 430.057 us; speedup vs baseline: 29.6996x; 1.3632x over previous
//
#include <hip/hip_runtime.h>

#define BATCH 1024
#define TT    200
#define EE    100
#define HH    200
#define GG    600   // 3*HH
#define NI    50000
#define NKT   7     // scan k-tiles: 224 = 7*32 (K=200 padded)
#define KPAD  224
#define HSTR  264   // LDS h row stride in f16
#define NTILE3 3125 // 50000/16 output n-tiles
#define NTW   50    // ewi n'-tiles: N'=800 = 50*16
#define KTW   4     // ewi k-tiles: K=100 padded to 128

typedef _Float16 half8 __attribute__((ext_vector_type(8)));
typedef _Float16 half4v __attribute__((ext_vector_type(4)));
typedef float   float4v __attribute__((ext_vector_type(4)));

static __device__ __forceinline__ float4v mfma16(half8 a, half8 b, float4v c) {
    return __builtin_amdgcn_mfma_f32_16x16x32_f16(a, b, c, 0, 0, 0);
}

#if __has_builtin(__builtin_amdgcn_rcpf)
static __device__ __forceinline__ float fastrcp(float x) { return __builtin_amdgcn_rcpf(x); }
#else
static __device__ __forceinline__ float fastrcp(float x) { return 1.f / x; }
#endif

static __device__ __forceinline__ float sigm(float x) {
    return fastrcp(1.f + __expf(-x));
}
static __device__ __forceinline__ float tanh_fast(float x) {
    float e = __expf(2.f * fabsf(x));
    float t = 1.f - 2.f * fastrcp(e + 1.f);
    return __builtin_copysignf(t, x);
}

// ---------------- K0a: repack Wi -> f16 MFMA B-frags, n' = 4c+g; also biP ----------------
// Wif[(nt*4+kt)*64 + lane] = B[k][n']: n'=nt*16+(lane&15), k=kt*32+(lane>>4)*8+j
// B[k][4c+g] = Wi[k][g*200+c] (g<3), 0 for g==3 or k>=100. biP[4c+g] = bi[g*200+c].
__global__ __launch_bounds__(64) void repack_wi(const float* __restrict__ Wi,
                                                const float* __restrict__ bi,
                                                half8* __restrict__ Wif,
                                                float* __restrict__ biP) {
    const int bx   = blockIdx.x;    // nt*4 + kt
    const int kt   = bx & 3;
    const int nt   = bx >> 2;
    const int lane = threadIdx.x;
    const int l15  = lane & 15;
    const int lhi  = lane >> 4;
    const int np   = nt * 16 + l15;     // n' in [0,800)
    const int c    = np >> 2;
    const int g    = np & 3;
    half8 v;
    #pragma unroll
    for (int j = 0; j < 8; ++j) {
        int k = kt * 32 + lhi * 8 + j;
        float w = (k < EE && g < 3) ? Wi[(size_t)k * GG + g * HH + c] : 0.f;
        v[j] = (_Float16)w;
    }
    Wif[(size_t)bx * 64 + lane] = v;
    if (kt == 0 && lhi == 0)
        biP[np] = (g < 3) ? bi[g * HH + c] : 0.f;
}

// ---------------- K1: EWi16 = embed @ Wi (+bi, row0=bi) via f16 MFMA ----------------
// 782 blocks x 4 waves; wave = one 16-row m-tile; streams 50 n-tiles x 4 k-tiles of
// register B-frags from L2-resident Wif. C-writes land directly in [v][c][4] layout.
__global__ __launch_bounds__(256) void ewi_mfma(const float* __restrict__ embed,
                                                const half8* __restrict__ Wif,
                                                const float* __restrict__ biP,
                                                _Float16* __restrict__ EWi16) {
    const int tid  = threadIdx.x;
    const int w    = tid >> 6;
    const int lane = tid & 63;
    const int l15  = lane & 15;
    const int lhi  = lane >> 4;

    const int mt = blockIdx.x * 4 + w;
    if (mt >= NTILE3) return;            // wave-uniform, no LDS/barriers in kernel
    const int i0 = mt * 16;

    // A-frags: a[kt][j] = embed[i0+l15][kt*32+lhi*8+j], f32 -> f16, 0 beyond K=100
    half8 a[KTW];
    #pragma unroll
    for (int kt = 0; kt < KTW; ++kt) {
        const int k0 = kt * 32 + lhi * 8;
        const float* er = embed + (size_t)(i0 + l15) * EE + k0;
        #pragma unroll
        for (int j = 0; j < 8; ++j)
            a[kt][j] = (k0 + j < EE) ? (_Float16)er[j] : (_Float16)0.f;
    }

    #pragma unroll 2
    for (int nt = 0; nt < NTW; ++nt) {
        const half8* bf = Wif + (size_t)nt * KTW * 64 + lane;
        float4v acc = (float4v){0.f, 0.f, 0.f, 0.f};
        #pragma unroll
        for (int kt = 0; kt < KTW; ++kt)
            acc = mfma16(a[kt], bf[kt * 64], acc);
        const float biv = biP[nt * 16 + l15];
        #pragma unroll
        for (int r = 0; r < 4; ++r) {
            const int row = i0 + lhi * 4 + r;
            float val = acc[r] + biv;
            if (row == 0) val = biv;     // q==0 padding row: masked embed -> bias only
            EWi16[(size_t)row * 800 + nt * 16 + l15] = (_Float16)val;
        }
    }
}

// ---------------- K1b: repack Wh -> f16 MFMA B-fragments ----------------
__global__ __launch_bounds__(64) void repack_whf(const float* __restrict__ Wh,
                                                 half8* __restrict__ Whf) {
    const int bx   = blockIdx.x;        // tile*7 + kt, tile = g*16+tc
    const int kt   = bx % NKT;
    const int tile = bx / NKT;
    const int g    = tile / 16;
    const int tc   = tile % 16;
    const int lane = threadIdx.x;
    const int col  = tc * 16 + (lane & 15);
    half8 v;
    #pragma unroll
    for (int j = 0; j < 8; ++j) {
        int k = kt * 32 + (lane >> 4) * 8 + j;
        float w = (k < HH && col < HH) ? Wh[(size_t)k * GG + g * HH + col] : 0.f;
        v[j] = (_Float16)w;
    }
    Whf[(size_t)bx * 64 + lane] = v;
}

// ---------------- K2: weight-stationary MFMA GRU scan, dense combine ----------------
// (unchanged from round 6 - at ~50% of its structural MFMA floor)
__global__ __launch_bounds__(512, 2) void scan_mfma(const int* __restrict__ q,
                                                    const _Float16* __restrict__ EWi16,
                                                    const half8* __restrict__ Whf,
                                                    const float* __restrict__ bhn,
                                                    _Float16* __restrict__ h16g) {
    __shared__ __align__(16) _Float16 hbuf[2][16 * HSTR];
    __shared__ __align__(16) float accbuf[48 * 16 * 4];   // [tilegate][col15][b]
    __shared__ int qs[4][TT];

    const int tid  = threadIdx.x;
    const int w    = tid >> 6;
    const int lane = tid & 63;
    const int l15  = lane & 15;
    const int lhi  = lane >> 4;     // = batch row b in combine
    const int b0   = blockIdx.x * 4;

    for (int idx = tid; idx < 2 * 16 * HSTR; idx += 512)
        ((_Float16*)hbuf)[idx] = (_Float16)0.f;
    for (int idx = tid; idx < 4 * TT; idx += 512) {
        int b = idx / TT, t = idx % TT;
        qs[b][t] = q[(size_t)(b0 + b) * TT + t];
    }

    // --- register-resident Wh fragments: [gate][c2][kt] ---
    half8 wb[3][2][7];
    #pragma unroll
    for (int g = 0; g < 3; ++g) {
        #pragma unroll
        for (int c2 = 0; c2 < 2; ++c2) {
            const int tc = w + c2 * 8;
            #pragma unroll
            for (int kt = 0; kt < NKT; ++kt)
                wb[g][c2][kt] = Whf[((size_t)(g * 16 + tc) * NKT + kt) * 64 + lane];
        }
    }

    const int col0 = w * 16 + l15;            // 0..127, always valid
    const int col1 = 128 + w * 16 + l15;      // 128..255, valid iff < 200
    const bool v1  = (col1 < HH);
    const int colw1 = v1 ? col1 : 236;        // dump slot (never read/exported)
    const float bh0 = bhn[col0];
    const float bh1 = v1 ? bhn[col1] : 0.f;

    float hreg0 = 0.f, hreg1 = 0.f;           // h_old for (b=lhi, col0/col1)

    __syncthreads();

    half4v giA0, giA1, giB0, giB1;
    #define LOADGI(d0, d1, tt) do {                                          \
        const int qv = qs[lhi][tt];                                          \
        const _Float16* ew = EWi16 + (size_t)qv * 800;                       \
        d0 = *(const half4v*)(ew + col0 * 4);                                \
        d1 = *(const half4v*)(ew + col1 * 4);                                \
    } while (0)

    LOADGI(giA0, giA1, 0);
    LOADGI(giB0, giB1, 1);

    #define STEP(CUR, NXT, G0, G1, TLOAD) do {                               \
        float4v acc[3][2];                                                   \
        _Pragma("unroll")                                                    \
        for (int g = 0; g < 3; ++g)                                          \
            _Pragma("unroll")                                                \
            for (int c2 = 0; c2 < 2; ++c2)                                   \
                acc[g][c2] = (float4v){0.f, 0.f, 0.f, 0.f};                  \
        const _Float16* hb = &hbuf[CUR][0];                                  \
        _Pragma("unroll")                                                    \
        for (int kt = 0; kt < NKT; ++kt) {                                   \
            const half8 af = *(const half8*)(hb + l15 * HSTR + kt * 32 + lhi * 8); \
            _Pragma("unroll")                                                \
            for (int g = 0; g < 3; ++g) {                                    \
                acc[g][0] = mfma16(af, wb[g][0][kt], acc[g][0]);             \
                acc[g][1] = mfma16(af, wb[g][1][kt], acc[g][1]);             \
            }                                                                \
        }                                                                    \
        /* redistribute: lanes 0-15 hold rows 0-3 (the real batch) */        \
        if (lane < 16) {                                                     \
            _Pragma("unroll")                                                \
            for (int g = 0; g < 3; ++g)                                      \
                _Pragma("unroll")                                            \
                for (int c2 = 0; c2 < 2; ++c2)                               \
                    *(float4v*)&accbuf[(((g * 16) + w + c2 * 8) * 16 + l15) * 4] = acc[g][c2]; \
        }                                                                    \
        /* dense combine: lane -> (b=lhi, col0|col1) */                      \
        _Float16* hn = &hbuf[NXT][0];                                        \
        {                                                                    \
            const int base0 = ((w) * 16 + l15) * 4 + lhi;                    \
            const int base1 = ((w + 8) * 16 + l15) * 4 + lhi;                \
            float aR0 = accbuf[0 * 1024 + base0];                            \
            float aZ0 = accbuf[1 * 1024 + base0];                            \
            float aN0 = accbuf[2 * 1024 + base0];                            \
            float aR1 = accbuf[0 * 1024 + base1];                            \
            float aZ1 = accbuf[1 * 1024 + base1];                            \
            float aN1 = accbuf[2 * 1024 + base1];                            \
            float r0 = sigm((float)G0[0] + aR0);                             \
            float z0 = sigm((float)G0[1] + aZ0);                             \
            float n0 = tanh_fast((float)G0[2] + r0 * (aN0 + bh0));           \
            float hv0 = (1.f - z0) * n0 + z0 * hreg0;                        \
            hreg0 = hv0;                                                     \
            hn[lhi * HSTR + col0] = (_Float16)hv0;                           \
            float r1 = sigm((float)G1[0] + aR1);                             \
            float z1 = sigm((float)G1[1] + aZ1);                             \
            float n1 = tanh_fast((float)G1[2] + r1 * (aN1 + bh1));           \
            float hv1 = (1.f - z1) * n1 + z1 * hreg1;                        \
            hreg1 = hv1;                                                     \
            hn[lhi * HSTR + colw1] = (_Float16)hv1;                          \
        }                                                                    \
        /* prefetch gi two steps ahead (overwrites the set just consumed) */ \
        {                                                                    \
            const int tl = (TLOAD) < TT ? (TLOAD) : (TT - 1);                \
            LOADGI(G0, G1, tl);                                              \
        }                                                                    \
        __syncthreads();                                                     \
    } while (0)

    for (int t = 0; t < TT; t += 2) {
        STEP(0, 1, giA0, giA1, t + 2);
        STEP(1, 0, giB0, giB1, t + 3);
    }
    #undef STEP
    #undef LOADGI

    // ---- export h_last (rows 0-3; k 200..223 are zeros from init) ----
    for (int idx = tid; idx < 4 * KPAD; idx += 512) {
        int b = idx / KPAD, k = idx % KPAD;
        h16g[(size_t)(b0 + b) * KPAD + k] = hbuf[0][b * HSTR + k];
    }
}

// ---------------- K3: out = h_last @ Wo + bo via f16 MFMA ----------------
__global__ __launch_bounds__(256) void out_mfma(const _Float16* __restrict__ h16g,
                                                const float* __restrict__ Wo,
                                                const float* __restrict__ bo,
                                                float* __restrict__ out) {
    const int tid  = threadIdx.x;
    const int w    = tid >> 6;
    const int lane = tid & 63;
    const int l15  = lane & 15;
    const int lhi  = lane >> 4;

    const int nt   = blockIdx.x * 4 + w;
    const bool live = (nt < NTILE3);
    const int ntc  = live ? nt : (NTILE3 - 1);
    const int col  = ntc * 16 + l15;

    half8 wb[7];
    #pragma unroll
    for (int kt = 0; kt < NKT; ++kt) {
        #pragma unroll
        for (int j = 0; j < 8; ++j) {
            int k = kt * 32 + lhi * 8 + j;
            wb[kt][j] = (k < HH) ? (_Float16)Wo[(size_t)k * NI + col] : (_Float16)0.f;
        }
    }
    const float bov = bo[col];

    for (int mt = 0; mt < BATCH / 16; ++mt) {
        const _Float16* hrow = h16g + (size_t)(mt * 16 + l15) * KPAD + lhi * 8;
        float4v acc = (float4v){0.f, 0.f, 0.f, 0.f};
        #pragma unroll
        for (int kt = 0; kt < NKT; ++kt) {
            const half8 af = *(const half8*)(hrow + kt * 32);
            acc = mfma16(af, wb[kt], acc);
        }
        if (live) {
            #pragma unroll
            for (int r = 0; r < 4; ++r) {
                int row = mt * 16 + lhi * 4 + r;
                out[(size_t)row * NI + col] = acc[r] + bov;
            }
        }
    }
}

extern "C" void kernel_launch(void* const* d_in, const int* in_sizes, int n_in,
                              void* d_out, int out_size, void* d_ws, size_t ws_size,
                              hipStream_t stream) {
    const int*   q     = (const int*)d_in[0];
    const float* embed = (const float*)d_in[1];
    const float* Wi    = (const float*)d_in[2];
    const float* bi    = (const float*)d_in[3];
    const float* Wh    = (const float*)d_in[4];
    const float* bhn   = (const float*)d_in[5];
    const float* Wo    = (const float*)d_in[6];
    const float* bo    = (const float*)d_in[7];
    float* out = (float*)d_out;

    // Scratch layout in d_out (204.8 MB), consumed before K3 overwrites it:
    //   EWi16 [50000 x 200 x 4] f16 = 80,000,000 B at +0
    //   Whf   [48*7 frags]      f16 =    344,064 B at +120,000,000
    //   Wif   [50*4 frags]      f16 =    204,800 B at +121,000,000
    //   biP   [800]             f32 =      3,200 B at +122,000,000
    //   h16g  [1024 x 224] f16 = 458,752 B in d_ws
    _Float16* EWi16 = (_Float16*)d_out;
    half8*    Whf   = (half8*)((char*)d_out + 120000000);
    half8*    Wif   = (half8*)((char*)d_out + 121000000);
    float*    biP   = (float*)((char*)d_out + 122000000);
    _Float16* h16g  = (_Float16*)d_ws;

    repack_wi<<<NTW * KTW, 64, 0, stream>>>(Wi, bi, Wif, biP);
    repack_whf<<<48 * NKT, 64, 0, stream>>>(Wh, Whf);
    ewi_mfma<<<(NTILE3 + 3) / 4, 256, 0, stream>>>(embed, Wif, biP, EWi16);
    scan_mfma<<<BATCH / 4, 512, 0, stream>>>(q, EWi16, Whf, bhn, h16g);
    out_mfma<<<(NTILE3 + 3) / 4, 256, 0, stream>>>(h16g, Wo, bo, out);
}

// Round 9
// 374.949 us; speedup vs baseline: 34.0647x; 1.1470x over previous
//
#include <hip/hip_runtime.h>

#define BATCH 1024
#define TT    200
#define EE    100
#define HH    200
#define GG    600   // 3*HH
#define NI    50000
#define NKT   7     // scan k-tiles: 224 = 7*32 (K=200 padded)
#define KPAD  224
#define HSTR  264   // LDS h row stride in f16
#define NTILE3 3125 // 50000/16 output n-tiles
#define NTW   50    // ewi n'-tiles: N'=800 = 50*16
#define KTW   4     // ewi k-tiles: K=100 padded to 128

typedef _Float16 half8 __attribute__((ext_vector_type(8)));
typedef _Float16 half4v __attribute__((ext_vector_type(4)));
typedef float   float4v __attribute__((ext_vector_type(4)));

static __device__ __forceinline__ float4v mfma16(half8 a, half8 b, float4v c) {
    return __builtin_amdgcn_mfma_f32_16x16x32_f16(a, b, c, 0, 0, 0);
}

#if __has_builtin(__builtin_amdgcn_rcpf)
static __device__ __forceinline__ float fastrcp(float x) { return __builtin_amdgcn_rcpf(x); }
#else
static __device__ __forceinline__ float fastrcp(float x) { return 1.f / x; }
#endif

static __device__ __forceinline__ float sigm(float x) {
    return fastrcp(1.f + __expf(-x));
}
static __device__ __forceinline__ float tanh_fast(float x) {
    float e = __expf(2.f * fabsf(x));
    float t = 1.f - 2.f * fastrcp(e + 1.f);
    return __builtin_copysignf(t, x);
}

// ---------------- K0: fused repack of Wi (+biP) and Wh into f16 MFMA B-frags ----------------
// bx < 200: Wif[(nt*4+kt)*64+lane], n'=4c+g packing; bx >= 200: Whf (48 gate-tiles x 7 kt).
__global__ __launch_bounds__(64) void repack_all(const float* __restrict__ Wi,
                                                 const float* __restrict__ bi,
                                                 const float* __restrict__ Wh,
                                                 half8* __restrict__ Wif,
                                                 float* __restrict__ biP,
                                                 half8* __restrict__ Whf) {
    const int bx   = blockIdx.x;
    const int lane = threadIdx.x;
    const int l15  = lane & 15;
    const int lhi  = lane >> 4;
    if (bx < NTW * KTW) {
        const int kt = bx & 3;
        const int nt = bx >> 2;
        const int np = nt * 16 + l15;     // n' in [0,800)
        const int c  = np >> 2;
        const int g  = np & 3;
        half8 v;
        #pragma unroll
        for (int j = 0; j < 8; ++j) {
            int k = kt * 32 + lhi * 8 + j;
            float w = (k < EE && g < 3) ? Wi[(size_t)k * GG + g * HH + c] : 0.f;
            v[j] = (_Float16)w;
        }
        Wif[(size_t)bx * 64 + lane] = v;
        if (kt == 0 && lhi == 0)
            biP[np] = (g < 3) ? bi[g * HH + c] : 0.f;
    } else {
        const int b2   = bx - NTW * KTW;   // 0..335
        const int kt   = b2 % NKT;
        const int tile = b2 / NKT;
        const int g    = tile / 16;
        const int tc   = tile % 16;
        const int col  = tc * 16 + l15;
        half8 v;
        #pragma unroll
        for (int j = 0; j < 8; ++j) {
            int k = kt * 32 + lhi * 8 + j;
            float w = (k < HH && col < HH) ? Wh[(size_t)k * GG + g * HH + col] : 0.f;
            v[j] = (_Float16)w;
        }
        Whf[(size_t)b2 * 64 + lane] = v;
    }
}

// ---------------- K1: EWi16 = embed @ Wi (+bi, row0=bi) via f16 MFMA, 2 m-tiles/wave ----------------
// B-frags (Wif) loaded once per nt and shared by both m-tiles -> halves L2 B traffic + loop overhead.
__global__ __launch_bounds__(256) void ewi_mfma(const float* __restrict__ embed,
                                                const half8* __restrict__ Wif,
                                                const float* __restrict__ biP,
                                                _Float16* __restrict__ EWi16) {
    const int tid  = threadIdx.x;
    const int w    = tid >> 6;
    const int lane = tid & 63;
    const int l15  = lane & 15;
    const int lhi  = lane >> 4;

    const int mtb   = (blockIdx.x * 4 + w) * 2;
    const bool liveA = (mtb < NTILE3);
    const bool liveB = (mtb + 1 < NTILE3);
    if (!liveA) return;                      // wave-uniform, kernel has no barriers
    const int i0a = mtb * 16;
    const int i0b = liveB ? (mtb + 1) * 16 : i0a;

    // A-frags for both m-tiles
    half8 aA[KTW], aB[KTW];
    #pragma unroll
    for (int kt = 0; kt < KTW; ++kt) {
        const int k0 = kt * 32 + lhi * 8;
        const float* erA = embed + (size_t)(i0a + l15) * EE + k0;
        const float* erB = embed + (size_t)(i0b + l15) * EE + k0;
        #pragma unroll
        for (int j = 0; j < 8; ++j) {
            aA[kt][j] = (k0 + j < EE) ? (_Float16)erA[j] : (_Float16)0.f;
            aB[kt][j] = (k0 + j < EE) ? (_Float16)erB[j] : (_Float16)0.f;
        }
    }

    for (int nt = 0; nt < NTW; ++nt) {
        const half8* bfp = Wif + (size_t)nt * KTW * 64 + lane;
        float4v accA = (float4v){0.f, 0.f, 0.f, 0.f};
        float4v accB = (float4v){0.f, 0.f, 0.f, 0.f};
        #pragma unroll
        for (int kt = 0; kt < KTW; ++kt) {
            const half8 bf = bfp[kt * 64];
            accA = mfma16(aA[kt], bf, accA);
            accB = mfma16(aB[kt], bf, accB);
        }
        const float biv = biP[nt * 16 + l15];
        #pragma unroll
        for (int r = 0; r < 4; ++r) {
            const int rowA = i0a + lhi * 4 + r;
            float valA = accA[r] + biv;
            if (rowA == 0) valA = biv;       // q==0 padding row: bias only
            EWi16[(size_t)rowA * 800 + nt * 16 + l15] = (_Float16)valA;
        }
        if (liveB) {
            #pragma unroll
            for (int r = 0; r < 4; ++r) {
                const int rowB = i0b + lhi * 4 + r;
                EWi16[(size_t)rowB * 800 + nt * 16 + l15] = (_Float16)(accB[r] + biv);
            }
        }
    }
}

// ---------------- K2: weight-stationary MFMA GRU scan, dense combine ----------------
// Round-8 change: accbuf re-indexed [l15][tile] with tile-stride 49 -> float4 writes
// and b32 reads both 2-way bank aliased (free) vs old layout's ~8-way on writes
// (measured 1.76e7 SQ_LDS_BANK_CONFLICT ~= 344 cy/step/CU, dominated by these writes).
__global__ __launch_bounds__(512, 2) void scan_mfma(const int* __restrict__ q,
                                                    const _Float16* __restrict__ EWi16,
                                                    const half8* __restrict__ Whf,
                                                    const float* __restrict__ bhn,
                                                    _Float16* __restrict__ h16g) {
    __shared__ __align__(16) _Float16 hbuf[2][16 * HSTR];
    __shared__ __align__(16) float accbuf[16 * 49 * 4];   // idx = ((l15*49 + tile)*4 + b)
    __shared__ int qs[4][TT];

    const int tid  = threadIdx.x;
    const int w    = tid >> 6;
    const int lane = tid & 63;
    const int l15  = lane & 15;
    const int lhi  = lane >> 4;     // = batch row b in combine
    const int b0   = blockIdx.x * 4;

    for (int idx = tid; idx < 2 * 16 * HSTR; idx += 512)
        ((_Float16*)hbuf)[idx] = (_Float16)0.f;
    for (int idx = tid; idx < 4 * TT; idx += 512) {
        int b = idx / TT, t = idx % TT;
        qs[b][t] = q[(size_t)(b0 + b) * TT + t];
    }

    // --- register-resident Wh fragments: [gate][c2][kt] ---
    half8 wb[3][2][7];
    #pragma unroll
    for (int g = 0; g < 3; ++g) {
        #pragma unroll
        for (int c2 = 0; c2 < 2; ++c2) {
            const int tc = w + c2 * 8;
            #pragma unroll
            for (int kt = 0; kt < NKT; ++kt)
                wb[g][c2][kt] = Whf[((size_t)(g * 16 + tc) * NKT + kt) * 64 + lane];
        }
    }

    const int col0 = w * 16 + l15;            // 0..127, always valid
    const int col1 = 128 + w * 16 + l15;      // 128..255, valid iff < 200
    const bool v1  = (col1 < HH);
    const int colw1 = v1 ? col1 : 236;        // dump slot (never read/exported)
    const float bh0 = bhn[col0];
    const float bh1 = v1 ? bhn[col1] : 0.f;

    float hreg0 = 0.f, hreg1 = 0.f;           // h_old for (b=lhi, col0/col1)

    __syncthreads();

    half4v giA0, giA1, giB0, giB1;
    #define LOADGI(d0, d1, tt) do {                                          \
        const int qv = qs[lhi][tt];                                          \
        const _Float16* ew = EWi16 + (size_t)qv * 800;                       \
        d0 = *(const half4v*)(ew + col0 * 4);                                \
        d1 = *(const half4v*)(ew + col1 * 4);                                \
    } while (0)

    LOADGI(giA0, giA1, 0);
    LOADGI(giB0, giB1, 1);

    #define STEP(CUR, NXT, G0, G1, TLOAD) do {                               \
        float4v acc[3][2];                                                   \
        _Pragma("unroll")                                                    \
        for (int g = 0; g < 3; ++g)                                          \
            _Pragma("unroll")                                                \
            for (int c2 = 0; c2 < 2; ++c2)                                   \
                acc[g][c2] = (float4v){0.f, 0.f, 0.f, 0.f};                  \
        const _Float16* hb = &hbuf[CUR][0];                                  \
        _Pragma("unroll")                                                    \
        for (int kt = 0; kt < NKT; ++kt) {                                   \
            const half8 af = *(const half8*)(hb + l15 * HSTR + kt * 32 + lhi * 8); \
            _Pragma("unroll")                                                \
            for (int g = 0; g < 3; ++g) {                                    \
                acc[g][0] = mfma16(af, wb[g][0][kt], acc[g][0]);             \
                acc[g][1] = mfma16(af, wb[g][1][kt], acc[g][1]);             \
            }                                                                \
        }                                                                    \
        /* redistribute: lanes 0-15 hold rows 0-3 (the real batch) */        \
        if (lane < 16) {                                                     \
            _Pragma("unroll")                                                \
            for (int g = 0; g < 3; ++g)                                      \
                _Pragma("unroll")                                            \
                for (int c2 = 0; c2 < 2; ++c2)                               \
                    *(float4v*)&accbuf[((l15 * 49) + (g * 16 + w + c2 * 8)) * 4] = acc[g][c2]; \
        }                                                                    \
        /* dense combine: lane -> (b=lhi, col0|col1) */                      \
        _Float16* hn = &hbuf[NXT][0];                                        \
        {                                                                    \
            const int rowb = l15 * 49 * 4 + lhi;                             \
            float aR0 = accbuf[rowb + (0 * 16 + w) * 4];                     \
            float aZ0 = accbuf[rowb + (1 * 16 + w) * 4];                     \
            float aN0 = accbuf[rowb + (2 * 16 + w) * 4];                     \
            float aR1 = accbuf[rowb + (0 * 16 + w + 8) * 4];                 \
            float aZ1 = accbuf[rowb + (1 * 16 + w + 8) * 4];                 \
            float aN1 = accbuf[rowb + (2 * 16 + w + 8) * 4];                 \
            float r0 = sigm((float)G0[0] + aR0);                             \
            float z0 = sigm((float)G0[1] + aZ0);                             \
            float n0 = tanh_fast((float)G0[2] + r0 * (aN0 + bh0));           \
            float hv0 = (1.f - z0) * n0 + z0 * hreg0;                        \
            hreg0 = hv0;                                                     \
            hn[lhi * HSTR + col0] = (_Float16)hv0;                           \
            float r1 = sigm((float)G1[0] + aR1);                             \
            float z1 = sigm((float)G1[1] + aZ1);                             \
            float n1 = tanh_fast((float)G1[2] + r1 * (aN1 + bh1));           \
            float hv1 = (1.f - z1) * n1 + z1 * hreg1;                        \
            hreg1 = hv1;                                                     \
            hn[lhi * HSTR + colw1] = (_Float16)hv1;                          \
        }                                                                    \
        /* prefetch gi two steps ahead (overwrites the set just consumed) */ \
        {                                                                    \
            const int tl = (TLOAD) < TT ? (TLOAD) : (TT - 1);                \
            LOADGI(G0, G1, tl);                                              \
        }                                                                    \
        __syncthreads();                                                     \
    } while (0)

    for (int t = 0; t < TT; t += 2) {
        STEP(0, 1, giA0, giA1, t + 2);
        STEP(1, 0, giB0, giB1, t + 3);
    }
    #undef STEP
    #undef LOADGI

    // ---- export h_last (rows 0-3; k 200..223 are zeros from init) ----
    for (int idx = tid; idx < 4 * KPAD; idx += 512) {
        int b = idx / KPAD, k = idx % KPAD;
        h16g[(size_t)(b0 + b) * KPAD + k] = hbuf[0][b * HSTR + k];
    }
}

// ---------------- K3: out = h_last @ Wo + bo via f16 MFMA, 2 n-tiles/wave ----------------
// A-frags (h rows) loaded once per m-tile and shared by both n-tiles -> halves
// h16g re-read traffic and mt-loop overhead.
__global__ __launch_bounds__(256) void out_mfma(const _Float16* __restrict__ h16g,
                                                const float* __restrict__ Wo,
                                                const float* __restrict__ bo,
                                                float* __restrict__ out) {
    const int tid  = threadIdx.x;
    const int w    = tid >> 6;
    const int lane = tid & 63;
    const int l15  = lane & 15;
    const int lhi  = lane >> 4;

    const int ntb   = (blockIdx.x * 4 + w) * 2;
    const bool liveA = (ntb < NTILE3);
    const bool liveB = (ntb + 1 < NTILE3);
    const int ntA = liveA ? ntb : (NTILE3 - 1);
    const int ntB = liveB ? (ntb + 1) : (NTILE3 - 1);
    const int colA = ntA * 16 + l15;
    const int colB = ntB * 16 + l15;

    half8 wbA[7], wbB[7];
    #pragma unroll
    for (int kt = 0; kt < NKT; ++kt) {
        #pragma unroll
        for (int j = 0; j < 8; ++j) {
            int k = kt * 32 + lhi * 8 + j;
            wbA[kt][j] = (k < HH) ? (_Float16)Wo[(size_t)k * NI + colA] : (_Float16)0.f;
            wbB[kt][j] = (k < HH) ? (_Float16)Wo[(size_t)k * NI + colB] : (_Float16)0.f;
        }
    }
    const float bovA = bo[colA];
    const float bovB = bo[colB];

    for (int mt = 0; mt < BATCH / 16; ++mt) {
        const _Float16* hrow = h16g + (size_t)(mt * 16 + l15) * KPAD + lhi * 8;
        float4v accA = (float4v){0.f, 0.f, 0.f, 0.f};
        float4v accB = (float4v){0.f, 0.f, 0.f, 0.f};
        #pragma unroll
        for (int kt = 0; kt < NKT; ++kt) {
            const half8 af = *(const half8*)(hrow + kt * 32);
            accA = mfma16(af, wbA[kt], accA);
            accB = mfma16(af, wbB[kt], accB);
        }
        if (liveA) {
            #pragma unroll
            for (int r = 0; r < 4; ++r) {
                int row = mt * 16 + lhi * 4 + r;
                out[(size_t)row * NI + colA] = accA[r] + bovA;
            }
        }
        if (liveB) {
            #pragma unroll
            for (int r = 0; r < 4; ++r) {
                int row = mt * 16 + lhi * 4 + r;
                out[(size_t)row * NI + colB] = accB[r] + bovB;
            }
        }
    }
}

extern "C" void kernel_launch(void* const* d_in, const int* in_sizes, int n_in,
                              void* d_out, int out_size, void* d_ws, size_t ws_size,
                              hipStream_t stream) {
    const int*   q     = (const int*)d_in[0];
    const float* embed = (const float*)d_in[1];
    const float* Wi    = (const float*)d_in[2];
    const float* bi    = (const float*)d_in[3];
    const float* Wh    = (const float*)d_in[4];
    const float* bhn   = (const float*)d_in[5];
    const float* Wo    = (const float*)d_in[6];
    const float* bo    = (const float*)d_in[7];
    float* out = (float*)d_out;

    // Scratch layout in d_out (204.8 MB), consumed before K3 overwrites it:
    //   EWi16 [50000 x 200 x 4] f16 = 80,000,000 B at +0
    //   Whf   [48*7 frags]      f16 =    344,064 B at +120,000,000
    //   Wif   [50*4 frags]      f16 =    204,800 B at +121,000,000
    //   biP   [800]             f32 =      3,200 B at +122,000,000
    //   h16g  [1024 x 224] f16 = 458,752 B in d_ws
    _Float16* EWi16 = (_Float16*)d_out;
    half8*    Whf   = (half8*)((char*)d_out + 120000000);
    half8*    Wif   = (half8*)((char*)d_out + 121000000);
    float*    biP   = (float*)((char*)d_out + 122000000);
    _Float16* h16g  = (_Float16*)d_ws;

    repack_all<<<NTW * KTW + 48 * NKT, 64, 0, stream>>>(Wi, bi, Wh, Wif, biP, Whf);
    ewi_mfma<<<(NTILE3 / 2 + 3) / 4, 256, 0, stream>>>(embed, Wif, biP, EWi16);
    scan_mfma<<<BATCH / 4, 512, 0, stream>>>(q, EWi16, Whf, bhn, h16g);
    out_mfma<<<(NTILE3 / 2 + 3) / 4 + 1, 256, 0, stream>>>(h16g, Wo, bo, out);
}